// Round 7
// baseline (28288.144 us; speedup 1.0000x reference)
//
#include <hip/hip_runtime.h>
#include <hip/hip_bf16.h>

typedef unsigned int u32;
typedef unsigned long long u64;
typedef float v2f __attribute__((ext_vector_type(2)));

#define NEGV (-1000000000.0f)
#define N_ANCH 261888
#define PRE_NMS 6000
#define POST_NMS 300

// ---------------- ws layout (bytes) ----------------
// scores_all : 0        (261888 f32)
// boxes_all  : 0x100000 (261888 float4)
// hist       : 0x500000 (4096 u32)
// cnts       : 0x504000 ([0]=cand_cnt [1]=nvalid [2]=bucketB)
// cand       : 0x505000 (8192 u64)
// nms_scores : 0x520000
// nms_boxes  : 0x526000
// mat        : 0x540000 (6000*94 u64 = 4.51MB)  } aliased: wt (2.36MB) lives here
// wt         : 0x540000 (64*36*256 f32)         } during conv, mat written after

__device__ __forceinline__ int bucket_of(float s) {
    if (!(s > 0.0f)) return 0;
    float t = s * 4096.0f;
    int b = (int)t;
    return b > 4095 ? 4095 : b;
}

// ================= K-1: weight transpose cw[oc][cf] -> wt[cf][oc]; also zero hist =================
__global__ void wtrans(const float* __restrict__ cw, float* __restrict__ wt, u32* __restrict__ hist) {
    int g = blockIdx.x * 256 + threadIdx.x;   // 589824 total
    int oc = g & 255; int cf = g >> 8;
    wt[g] = cw[oc * 2304 + cf];
    if (g < 4104) hist[g] = 0u;               // hist(4096) + cnts(8)
}

// ================= K1: fused conv3x3+relu + heads + decode, ALL levels =================
// block 256 threads; tile = 8 rows x 4 cols x all 256 oc; NO LDS / NO barriers in main loop:
//  - inputs are block-uniform -> scalar loads (SMEM pipe), clamped addresses + uniform selects
//  - weights read directly from global wt[cf][oc] (coalesced dword, L2-resident)
// acc pairs rows (ty, ty+4); per-output accumulation order identical to R5 (bit-exact).
__global__ __launch_bounds__(256, 6) void conv_head(
    const float* __restrict__ p2, const float* __restrict__ p3,
    const float* __restrict__ p4, const float* __restrict__ p5,
    const float* __restrict__ p6,
    const float* __restrict__ wt, const float* __restrict__ cb,
    const float* __restrict__ lw, const float* __restrict__ lb,
    const float* __restrict__ sw, const float* __restrict__ sb,
    float* __restrict__ scores_all, float4* __restrict__ boxes_all)
{
    __shared__ float smem[4480];              // epilogue only: hl[16][260] + ob[16][20]
    const int tid  = threadIdx.x;

    int bid = blockIdx.x;
    const float* in; int W, stride, abase, local, lgx;
    if (bid < 2048)      { in = p2; W = 256; stride = 4;  abase = 0;      local = bid;        lgx = 6; }
    else if (bid < 2560) { in = p3; W = 128; stride = 8;  abase = 196608; local = bid - 2048; lgx = 5; }
    else if (bid < 2688) { in = p4; W = 64;  stride = 16; abase = 245760; local = bid - 2560; lgx = 4; }
    else if (bid < 2720) { in = p5; W = 32;  stride = 32; abase = 258048; local = bid - 2688; lgx = 3; }
    else                 { in = p6; W = 16;  stride = 64; abase = 261120; local = bid - 2720; lgx = 2; }
    const int bx = local & ((1 << lgx) - 1), by = local >> lgx;
    const int gx0 = bx * 4, gy0 = by * 8;
    const int HW = W * W;

    v2f acc2[4][4];                           // [row-pair][col]; .x=row tp, .y=row tp+4
#pragma unroll
    for (int i = 0; i < 4; ++i)
#pragma unroll
        for (int j = 0; j < 4; ++j) acc2[i][j] = (v2f){0.0f, 0.0f};

    // uniform column geometry (shared by all rows)
    int xc_[6]; bool okx_[6];
#pragma unroll
    for (int cc = 0; cc < 6; ++cc) {
        int xcol = gx0 - 1 + cc;
        okx_[cc] = (xcol >= 0) && (xcol < W);
        xc_[cc] = xcol < 0 ? 0 : (xcol >= W ? W - 1 : xcol);
    }

    const float* wbase = wt + tid;            // column oc = tid

    for (int c = 0; c < 128; ++c) {           // 128 chunks of 2 ic
#pragma unroll
        for (int ic = 0; ic < 2; ++ic) {
            const int ch = c * 2 + ic;
            const float* ibase = in + (size_t)ch * HW;

            // ---- uniform halo load h[10][6] (scalar path; clamped addresses) ----
            float h[10][6];
#pragma unroll
            for (int r = 0; r < 10; ++r) {
                int yg = gy0 - 1 + r;
                bool oky = (yg >= 0) && (yg < W);
                int yc = yg < 0 ? 0 : (yg >= W ? W - 1 : yg);
                const float* rowp = ibase + yc * W;
#pragma unroll
                for (int cc = 0; cc < 6; ++cc) {
                    float raw = rowp[xc_[cc]];
                    h[r][cc] = (oky && okx_[cc]) ? raw : 0.0f;
                }
            }
            // ---- per-thread weights (coalesced, L2-hot) ----
            v2f wk2[9];
#pragma unroll
            for (int k = 0; k < 9; ++k) {
                float w_ = wbase[(ch * 9 + k) * 256];
                wk2[k] = (v2f){w_, w_};
            }
            // ---- FMA: stream pair-rows, all pk operands natural pairs ----
#pragma unroll
            for (int hr = 0; hr < 6; ++hr) {
                v2f hp[6];
#pragma unroll
                for (int cc = 0; cc < 6; ++cc)
                    hp[cc] = (v2f){h[hr][cc], h[hr + 4][cc]};
#pragma unroll
                for (int dy = 0; dy < 3; ++dy) {
                    const int tp = hr - dy;
                    if (tp >= 0 && tp < 4) {
#pragma unroll
                        for (int tx = 0; tx < 4; ++tx)
#pragma unroll
                            for (int dx = 0; dx < 3; ++dx)
                                acc2[tp][tx] = __builtin_elementwise_fma(wk2[dy * 3 + dx], hp[tx + dx], acc2[tp][tx]);
                    }
                }
            }
        }
    }
    // bias + relu (oc = tid); both pair halves share bias
    {
        float bvv = cb[tid];
#pragma unroll
        for (int i = 0; i < 4; ++i)
#pragma unroll
            for (int j = 0; j < 4; ++j) {
                v2f t = acc2[i][j];
                t.x = fmaxf(t.x + bvv, 0.0f);
                t.y = fmaxf(t.y + bvv, 0.0f);
                acc2[i][j] = t;
            }
    }
    // epilogue LDS: hl[16][260]@0, ob[16][20]@4160 ; head weights read from global (L2-hot)
    float* hl = smem;
    float* ob = smem + 4160;

    for (int g = 0; g < 2; ++g) {             // group g: rows g*4 .. g*4+3
        __syncthreads();
#pragma unroll
        for (int p = 0; p < 16; ++p) {
            const int pr = p >> 2, tx = p & 3;
            hl[p * 260 + tid] = g ? acc2[pr][tx].y : acc2[pr][tx].x;
        }
        __syncthreads();
        for (int it = tid; it < 288; it += 256) {
            int px = it / 18, o = it - px * 18;
            float a = (o < 12) ? lb[o] : sb[o - 12];
            const float* wrow = (o < 12) ? (lw + o * 256) : (sw + (o - 12) * 256);
            const float4* hv4 = (const float4*)&hl[px * 260];
            const float4* wv4 = (const float4*)wrow;
#pragma unroll 8
            for (int cc = 0; cc < 64; ++cc) {
                float4 hv = hv4[cc], wq = wv4[cc];
                a += hv.x * wq.x; a += hv.y * wq.y; a += hv.z * wq.z; a += hv.w * wq.w;
            }
            ob[px * 20 + o] = a;
        }
        __syncthreads();
        if (tid < 48) {
            int px = tid / 3, a = tid - px * 3;
            int gy = gy0 + (g << 2) + (px >> 2);
            int gx = gx0 + (px & 3);
            float dy = ob[px * 20 + a * 4 + 0];
            float dx = ob[px * 20 + a * 4 + 1];
            float dh = ob[px * 20 + a * 4 + 2];
            float dw = ob[px * 20 + a * 4 + 3];
            float s0 = ob[px * 20 + 12 + a * 2];
            float s1 = ob[px * 20 + 13 + a * 2];
            float mm = fmaxf(s0, s1);
            float e0 = expf(s0 - mm), e1x = expf(s1 - mm);
            float fg = e1x / (e0 + e1x);
            float sqa = (a == 0) ? 0.70710678f : ((a == 1) ? 1.0f : 1.41421356f);
            float sqb = (a == 0) ? 1.41421356f : ((a == 1) ? 1.0f : 0.70710678f);
            float s8 = (float)(stride * 8);
            float hs = __fmul_rn(s8, sqa), wsz = __fmul_rn(s8, sqb);
            float g_y = (float)(gy * stride), g_x = (float)(gx * stride);
            float a_y1 = __fsub_rn(g_y, __fmul_rn(hs, 0.5f));
            float a_y2 = __fadd_rn(g_y, __fmul_rn(hs, 0.5f));
            float a_x1 = __fsub_rn(g_x, __fmul_rn(wsz, 0.5f));
            float a_x2 = __fadd_rn(g_x, __fmul_rn(wsz, 0.5f));
            float ah = __fsub_rn(a_y2, a_y1), aw = __fsub_rn(a_x2, a_x1);
            float acy = __fadd_rn(a_y1, __fmul_rn(0.5f, ah));
            float acx = __fadd_rn(a_x1, __fmul_rn(0.5f, aw));
            float cy = __fadd_rn(__fmul_rn(dy, ah), acy);
            float cx = __fadd_rn(__fmul_rn(dx, aw), acx);
            float bh = __fmul_rn(expf(dh), ah);
            float bw = __fmul_rn(expf(dw), aw);
            float y1 = __fsub_rn(cy, __fmul_rn(0.5f, bh));
            float x1 = __fsub_rn(cx, __fmul_rn(0.5f, bw));
            float y2 = __fadd_rn(cy, __fmul_rn(0.5f, bh));
            float x2 = __fadd_rn(cx, __fmul_rn(0.5f, bw));
            y1 = fminf(fmaxf(y1, 0.0f), 1024.0f); x1 = fminf(fmaxf(x1, 0.0f), 1024.0f);
            y2 = fminf(fmaxf(y2, 0.0f), 1024.0f); x2 = fminf(fmaxf(x2, 0.0f), 1024.0f);
            float hh2 = __fsub_rn(y2, y1), ww2 = __fsub_rn(x2, x1);
            float sc = (hh2 >= 16.0f && ww2 >= 16.0f) ? fg : NEGV;
            int A = abase + (gy * W + gx) * 3 + a;
            scores_all[A] = sc;
            boxes_all[A] = make_float4(y1, x1, y2, x2);
        }
    }
}

// ================= K2: score histogram (4096 buckets) =================
__global__ void hist_k(const float* __restrict__ scores, u32* __restrict__ hist) {
    __shared__ u32 h[4096];
    int tid = threadIdx.x;
    for (int i = tid; i < 4096; i += 256) h[i] = 0u;
    __syncthreads();
    int gid = blockIdx.x * 256 + tid;
    int gs = gridDim.x * 256;
    for (int i = gid; i < N_ANCH; i += gs)
        atomicAdd(&h[bucket_of(scores[i])], 1u);
    __syncthreads();
    for (int i = tid; i < 4096; i += 256) if (h[i]) atomicAdd(&hist[i], h[i]);
}

// ================= K3: find cutoff bucket (single wave) =================
__global__ void select_bucket(const u32* __restrict__ hist, u32* __restrict__ cnts) {
    int lane = threadIdx.x;
    u32 S = 0;
    for (int c = 0; c < 64; ++c) {
        int bin = 4095 - (c * 64 + lane);
        u32 cnt = hist[bin];
        u32 cum = cnt;
        for (int off = 1; off < 64; off <<= 1) {
            u32 n = __shfl_up(cum, off, 64);
            if (lane >= off) cum += n;
        }
        u64 ball = __ballot(S + cum >= (u32)PRE_NMS);
        if (ball) {
            int l = __ffsll((long long)ball) - 1;
            if (lane == 0) cnts[2] = (u32)(4095 - (c * 64 + l));
            return;
        }
        S += __shfl(cum, 63, 64);
    }
    if (lane == 0) cnts[2] = 0u;
}

// ================= K4: compact candidates (bucket >= B) =================
__global__ void compact_k(const float* __restrict__ scores, u32* __restrict__ cnts,
                          u64* __restrict__ cand) {
    int B = (int)cnts[2];
    int gid = blockIdx.x * blockDim.x + threadIdx.x;
    int gs = gridDim.x * blockDim.x;
    for (int i = gid; i < N_ANCH; i += gs) {
        float s = scores[i];
        if (bucket_of(s) >= B) {
            u32 pos = atomicAdd(&cnts[0], 1u);
            if (pos < 8192u) {
                u32 u = __float_as_uint(s);
                u32 key = (u & 0x80000000u) ? ~u : (u | 0x80000000u);
                cand[pos] = ((u64)key << 32) | (u64)((u32)(~i));
            }
        }
    }
}

// ================= K5: bitonic sort (desc) + gather top-6000 =================
__global__ __launch_bounds__(1024) void sort_gather(
    const u64* __restrict__ cand, const u32* __restrict__ cnts,
    const float* __restrict__ sall, const float4* __restrict__ ball,
    float* __restrict__ nsc, float4* __restrict__ nbx, u32* __restrict__ nvalid)
{
    __shared__ u64 srt[8192];
    int tid = threadIdx.x;
    u32 total = cnts[0]; if (total > 8192u) total = 8192u;
    for (int i = tid; i < 8192; i += 1024) srt[i] = (i < (int)total) ? cand[i] : 0ULL;
    __syncthreads();
    for (int k = 2; k <= 8192; k <<= 1) {
        for (int j = k >> 1; j > 0; j >>= 1) {
            for (int i = tid; i < 8192; i += 1024) {
                int l = i ^ j;
                if (l > i) {
                    u64 a = srt[i], b = srt[l];
                    bool descRegion = (i & k) == 0;
                    if (descRegion ? (a < b) : (a > b)) { srt[i] = b; srt[l] = a; }
                }
            }
            __syncthreads();
        }
    }
    int local = 0;
    for (int i = tid; i < PRE_NMS; i += 1024) {
        u64 comp = srt[i];
        u32 idx = ~((u32)(comp & 0xFFFFFFFFULL));
        float s; float4 bx;
        if (idx < (u32)N_ANCH) { s = sall[idx]; bx = ball[idx]; }
        else { s = NEGV; bx = make_float4(0.f, 0.f, 0.f, 0.f); }
        nsc[i] = s;
        nbx[i] = bx;
        if (s > -5.0e8f) local++;
    }
    for (int off = 32; off > 0; off >>= 1) local += __shfl_down(local, off, 64);
    if ((tid & 63) == 0) atomicAdd(nvalid, (u32)local);
}

// ================= K6: IoU suppression bitmask matrix =================
__global__ void ioumat(const float4* __restrict__ bxs, u64* __restrict__ mat) {
    int i = blockIdx.x;
    int w = threadIdx.x;
    if (w >= 94) return;
    float4 bi = bxs[i];
    float a1 = (bi.z - bi.x) * (bi.w - bi.y);
    u64 bits = 0ULL;
    int j0 = w * 64;
    for (int b = 0; b < 64; ++b) {
        int j = j0 + b;
        if (j < PRE_NMS) {
            float4 bj = bxs[j];
            float ty = fmaxf(bi.x, bj.x), tx = fmaxf(bi.y, bj.y);
            float by = fminf(bi.z, bj.z), bx = fminf(bi.w, bj.w);
            float inter = fmaxf(by - ty, 0.0f) * fmaxf(bx - tx, 0.0f);
            float a2 = (bj.z - bj.x) * (bj.w - bj.y);
            float iou = inter / fmaxf(a1 + a2 - inter, 1e-9f);
            if (iou > 0.7f) bits |= (1ULL << b);
        }
    }
    mat[(size_t)i * 94 + w] = bits;
}

// ================= K7: greedy NMS, suppression state in registers =================
__global__ void greedy(const u64* __restrict__ mat, const float* __restrict__ nbxf,
                       const u32* __restrict__ nvalid, float* __restrict__ out) {
    int lane = threadIdx.x;   // 64
    u64 rem0 = 0ULL, rem1 = 0ULL;   // lane owns words {lane, 64+lane}
    int nv = (int)*nvalid; if (nv > PRE_NMS) nv = PRE_NMS;
    int kept = 0;
    for (int widx = 0; widx * 64 < nv && kept < POST_NMS; ++widx) {
        u64 word = (widx < 64) ? __shfl(rem0, widx, 64) : __shfl(rem1, widx - 64, 64);
        int bmax = nv - widx * 64; if (bmax > 64) bmax = 64;
        for (int b = 0; b < bmax; ++b) {
            if (!((word >> b) & 1ULL)) {
                int i = widx * 64 + b;
                const u64* row = mat + (size_t)i * 94;
                rem0 |= row[lane];
                if (lane < 30) rem1 |= row[64 + lane];
                if (lane < 4) out[kept * 4 + lane] = nbxf[i * 4 + lane];
                ++kept;
                if (kept == POST_NMS) break;
                word = (widx < 64) ? __shfl(rem0, widx, 64) : __shfl(rem1, widx - 64, 64);
            }
        }
        if (kept == POST_NMS) break;
    }
    for (int idx = kept * 4 + lane; idx < POST_NMS * 4; idx += 64) out[idx] = 0.0f;
}

// ================= host =================
extern "C" void kernel_launch(void* const* d_in, const int* in_sizes, int n_in,
                              void* d_out, int out_size, void* d_ws, size_t ws_size,
                              hipStream_t stream) {
    const float* p2 = (const float*)d_in[0];
    const float* p3 = (const float*)d_in[1];
    const float* p4 = (const float*)d_in[2];
    const float* p5 = (const float*)d_in[3];
    const float* p6 = (const float*)d_in[4];
    const float* cw = (const float*)d_in[5];
    const float* cb = (const float*)d_in[6];
    const float* lw = (const float*)d_in[7];
    const float* lb = (const float*)d_in[8];
    const float* sw = (const float*)d_in[9];
    const float* sb = (const float*)d_in[10];
    float* out = (float*)d_out;
    char* ws = (char*)d_ws;

    float*  scores_all = (float*)(ws + 0);
    float4* boxes_all  = (float4*)(ws + 0x100000);
    u32*    hist       = (u32*)(ws + 0x500000);
    u32*    cnts       = (u32*)(ws + 0x504000);
    u64*    cand       = (u64*)(ws + 0x505000);
    float*  nsc        = (float*)(ws + 0x520000);
    float4* nbx        = (float4*)(ws + 0x526000);
    u64*    mat        = (u64*)(ws + 0x540000);
    float*  wt         = (float*)(ws + 0x540000);  // aliases mat (conv-phase only)

    hipLaunchKernelGGL(wtrans, dim3(2304), dim3(256), 0, stream, cw, wt, hist);
    hipLaunchKernelGGL(conv_head, dim3(2728), dim3(256), 0, stream,
                       p2, p3, p4, p5, p6, wt, cb, lw, lb, sw, sb,
                       scores_all, boxes_all);
    hipLaunchKernelGGL(hist_k, dim3(64), dim3(256), 0, stream, scores_all, hist);
    hipLaunchKernelGGL(select_bucket, dim3(1), dim3(64), 0, stream, hist, cnts);
    hipLaunchKernelGGL(compact_k, dim3(512), dim3(256), 0, stream, scores_all, cnts, cand);
    hipLaunchKernelGGL(sort_gather, dim3(1), dim3(1024), 0, stream,
                       cand, cnts, scores_all, boxes_all, nsc, nbx, cnts + 1);
    hipLaunchKernelGGL(ioumat, dim3(PRE_NMS), dim3(128), 0, stream, nbx, mat);
    hipLaunchKernelGGL(greedy, dim3(1), dim3(64), 0, stream, mat, (const float*)nbx, cnts + 1, out);
}

// Round 8
// 1885.284 us; speedup vs baseline: 15.0047x; 15.0047x over previous
//
#include <hip/hip_runtime.h>
#include <hip/hip_bf16.h>

typedef unsigned int u32;
typedef unsigned long long u64;
typedef float v2f __attribute__((ext_vector_type(2)));
typedef float v4f __attribute__((ext_vector_type(4)));

#define NEGV (-1000000000.0f)
#define N_ANCH 261888
#define PRE_NMS 6000
#define POST_NMS 300

// ---------------- ws layout (bytes) ----------------
// scores_all : 0        (261888 f32)
// boxes_all  : 0x100000 (261888 float4)
// hist       : 0x500000 (4096 u32)
// cnts       : 0x504000 ([0]=cand_cnt [1]=nvalid [2]=bucketB)
// cand       : 0x505000 (8192 u64)
// nms_scores : 0x520000
// nms_boxes  : 0x526000
// mat        : 0x540000 (6000*94 u64 = 4.51MB)  } aliased: wtk (3.15MB) lives here
// wtk        : 0x540000 (256ch*256oc*12 f32)    } during conv, mat written after

__device__ __forceinline__ int bucket_of(float s) {
    if (!(s > 0.0f)) return 0;
    float t = s * 4096.0f;
    int b = (int)t;
    return b > 4095 ? 4095 : b;
}

// ================= K-1: weight relayout cw[oc][ch*9+k] -> wtk[ch][oc][12]; also zero hist =================
__global__ void wtrans(const float* __restrict__ cw, float* __restrict__ wtk, u32* __restrict__ hist) {
    int g = blockIdx.x * 256 + threadIdx.x;   // 786432 total
    int k = g % 12; int rest = g / 12;
    int oc = rest & 255; int ch = rest >> 8;
    wtk[g] = (k < 9) ? cw[oc * 2304 + ch * 9 + k] : 0.0f;
    if (g < 4104) hist[g] = 0u;               // hist(4096) + cnts(8)
}

// ================= K1: fused conv3x3+relu + heads + decode, ALL levels =================
// block 256 threads; tile = 8 rows x 4 cols x all 256 oc; ic-chunks of 4.
// Inputs staged in LDS as row-pairs (proven R5 structure, no spill);
// weights read per-thread from global wtk[ch][oc][12] (3x float4, L2-hot) -> no weight LDS, half the barriers.
// acc pairs rows (ty, ty+4); per-output accumulation order identical to R5 (bit-exact).
__global__ __launch_bounds__(256, 6) void conv_head(
    const float* __restrict__ p2, const float* __restrict__ p3,
    const float* __restrict__ p4, const float* __restrict__ p5,
    const float* __restrict__ p6,
    const float* __restrict__ wtk, const float* __restrict__ cb,
    const float* __restrict__ lw, const float* __restrict__ lb,
    const float* __restrict__ sw, const float* __restrict__ sb,
    float* __restrict__ scores_all, float4* __restrict__ boxes_all)
{
    __shared__ float smem[6656];              // 26624 B -> pins exactly 6 blocks/CU
    v2f* IpL = (v2f*)(smem + 4608);           // [4 ic][6 iy][8 pad] v2f = 192 v2f
    const int tid  = threadIdx.x;
    const int wv   = tid >> 6;                // wave id 0..3 (= ic within chunk)
    const int lane = tid & 63;

    int bid = blockIdx.x;
    const float* in; int W, stride, abase, local, lgx;
    if (bid < 2048)      { in = p2; W = 256; stride = 4;  abase = 0;      local = bid;        lgx = 6; }
    else if (bid < 2560) { in = p3; W = 128; stride = 8;  abase = 196608; local = bid - 2048; lgx = 5; }
    else if (bid < 2688) { in = p4; W = 64;  stride = 16; abase = 245760; local = bid - 2560; lgx = 4; }
    else if (bid < 2720) { in = p5; W = 32;  stride = 32; abase = 258048; local = bid - 2688; lgx = 3; }
    else                 { in = p6; W = 16;  stride = 64; abase = 261120; local = bid - 2720; lgx = 2; }
    const int bx = local & ((1 << lgx) - 1), by = local >> lgx;
    const int gx0 = bx * 4, gy0 = by * 8;
    const int HW = W * W;

    v2f acc2[4][4];                           // [row-pair][col]; .x=row tp, .y=row tp+4
#pragma unroll
    for (int i = 0; i < 4; ++i)
#pragma unroll
        for (int j = 0; j < 4; ++j) acc2[i][j] = (v2f){0.0f, 0.0f};

    // staging: wave wv stages ic=wv; lane<36: pair (iy=lane/6, xx=lane%6)
    const int iy = lane / 6, xx = lane - iy * 6;
    const int ylo = gy0 - 1 + iy, yhi = ylo + 4, xg = gx0 - 1 + xx;
    const bool act = (lane < 36);
    const bool aLo = act && (ylo >= 0 && ylo < W && xg >= 0 && xg < W);
    const bool aHi = act && (yhi >= 0 && yhi < W && xg >= 0 && xg < W);
    const int ofsLo = ylo * W + xg;
    const int ofsHi = yhi * W + xg;
    const int ipidx = (wv * 6 + iy) * 8 + xx;

    for (int c = 0; c < 64; ++c) {            // 64 chunks of 4 ic
        __syncthreads();
        // ---- stage paired input halo for ic=wv: Ip[wv][iy][xx] = {row iy, row iy+4} ----
        const float* ibase = in + (size_t)(c * 4 + wv) * HW;
        if (act) {
            float vlo = aLo ? ibase[ofsLo] : 0.0f;
            float vhi = aHi ? ibase[ofsHi] : 0.0f;
            IpL[ipidx] = (v2f){vlo, vhi};
        }
        __syncthreads();
        // ---- compute: weights from global (L2-hot), inputs from LDS broadcast ----
#pragma unroll
        for (int ic = 0; ic < 4; ++ic) {
            const int ch = c * 4 + ic;
            const v4f* wq = (const v4f*)(wtk + (size_t)ch * 3072 + tid * 12);
            v4f w0 = wq[0], w1 = wq[1], w2 = wq[2];
            v2f wk2[9];
            wk2[0] = (v2f){w0.x, w0.x}; wk2[1] = (v2f){w0.y, w0.y}; wk2[2] = (v2f){w0.z, w0.z};
            wk2[3] = (v2f){w0.w, w0.w}; wk2[4] = (v2f){w1.x, w1.x}; wk2[5] = (v2f){w1.y, w1.y};
            wk2[6] = (v2f){w1.z, w1.z}; wk2[7] = (v2f){w1.w, w1.w}; wk2[8] = (v2f){w2.x, w2.x};
#pragma unroll
            for (int ip = 0; ip < 6; ++ip) {
                const v4f* rq = (const v4f*)&IpL[(ic * 6 + ip) * 8];
                v4f q0 = rq[0], q1 = rq[1], q2 = rq[2];
                v2f iw[6];
                iw[0] = __builtin_shufflevector(q0, q0, 0, 1);
                iw[1] = __builtin_shufflevector(q0, q0, 2, 3);
                iw[2] = __builtin_shufflevector(q1, q1, 0, 1);
                iw[3] = __builtin_shufflevector(q1, q1, 2, 3);
                iw[4] = __builtin_shufflevector(q2, q2, 0, 1);
                iw[5] = __builtin_shufflevector(q2, q2, 2, 3);
#pragma unroll
                for (int dy = 0; dy < 3; ++dy) {
                    const int tp = ip - dy;
                    if (tp >= 0 && tp < 4) {
#pragma unroll
                        for (int tx = 0; tx < 4; ++tx)
#pragma unroll
                            for (int dx = 0; dx < 3; ++dx)
                                acc2[tp][tx] = __builtin_elementwise_fma(wk2[dy * 3 + dx], iw[tx + dx], acc2[tp][tx]);
                    }
                }
            }
        }
    }
    // bias + relu (oc = tid); both pair halves share bias
    {
        float bvv = cb[tid];
#pragma unroll
        for (int i = 0; i < 4; ++i)
#pragma unroll
            for (int j = 0; j < 4; ++j) {
                v2f t = acc2[i][j];
                t.x = fmaxf(t.x + bvv, 0.0f);
                t.y = fmaxf(t.y + bvv, 0.0f);
                acc2[i][j] = t;
            }
    }
    // epilogue LDS: hl[16][260]@0, ob[16][20]@4160 ; head weights read from global (L2-hot)
    float* hl = smem;
    float* ob = smem + 4160;

    for (int g = 0; g < 2; ++g) {             // group g: rows g*4 .. g*4+3
        __syncthreads();
#pragma unroll
        for (int p = 0; p < 16; ++p) {
            const int pr = p >> 2, tx = p & 3;
            hl[p * 260 + tid] = g ? acc2[pr][tx].y : acc2[pr][tx].x;
        }
        __syncthreads();
        for (int it = tid; it < 288; it += 256) {
            int px = it / 18, o = it - px * 18;
            float a = (o < 12) ? lb[o] : sb[o - 12];
            const float* wrow = (o < 12) ? (lw + o * 256) : (sw + (o - 12) * 256);
            const float4* hv4 = (const float4*)&hl[px * 260];
            const float4* wv4 = (const float4*)wrow;
#pragma unroll 8
            for (int cc = 0; cc < 64; ++cc) {
                float4 hv = hv4[cc], wq = wv4[cc];
                a += hv.x * wq.x; a += hv.y * wq.y; a += hv.z * wq.z; a += hv.w * wq.w;
            }
            ob[px * 20 + o] = a;
        }
        __syncthreads();
        if (tid < 48) {
            int px = tid / 3, a = tid - px * 3;
            int gy = gy0 + (g << 2) + (px >> 2);
            int gx = gx0 + (px & 3);
            float dy = ob[px * 20 + a * 4 + 0];
            float dx = ob[px * 20 + a * 4 + 1];
            float dh = ob[px * 20 + a * 4 + 2];
            float dw = ob[px * 20 + a * 4 + 3];
            float s0 = ob[px * 20 + 12 + a * 2];
            float s1 = ob[px * 20 + 13 + a * 2];
            float mm = fmaxf(s0, s1);
            float e0 = expf(s0 - mm), e1x = expf(s1 - mm);
            float fg = e1x / (e0 + e1x);
            float sqa = (a == 0) ? 0.70710678f : ((a == 1) ? 1.0f : 1.41421356f);
            float sqb = (a == 0) ? 1.41421356f : ((a == 1) ? 1.0f : 0.70710678f);
            float s8 = (float)(stride * 8);
            float hs = __fmul_rn(s8, sqa), wsz = __fmul_rn(s8, sqb);
            float g_y = (float)(gy * stride), g_x = (float)(gx * stride);
            float a_y1 = __fsub_rn(g_y, __fmul_rn(hs, 0.5f));
            float a_y2 = __fadd_rn(g_y, __fmul_rn(hs, 0.5f));
            float a_x1 = __fsub_rn(g_x, __fmul_rn(wsz, 0.5f));
            float a_x2 = __fadd_rn(g_x, __fmul_rn(wsz, 0.5f));
            float ah = __fsub_rn(a_y2, a_y1), aw = __fsub_rn(a_x2, a_x1);
            float acy = __fadd_rn(a_y1, __fmul_rn(0.5f, ah));
            float acx = __fadd_rn(a_x1, __fmul_rn(0.5f, aw));
            float cy = __fadd_rn(__fmul_rn(dy, ah), acy);
            float cx = __fadd_rn(__fmul_rn(dx, aw), acx);
            float bh = __fmul_rn(expf(dh), ah);
            float bw = __fmul_rn(expf(dw), aw);
            float y1 = __fsub_rn(cy, __fmul_rn(0.5f, bh));
            float x1 = __fsub_rn(cx, __fmul_rn(0.5f, bw));
            float y2 = __fadd_rn(cy, __fmul_rn(0.5f, bh));
            float x2 = __fadd_rn(cx, __fmul_rn(0.5f, bw));
            y1 = fminf(fmaxf(y1, 0.0f), 1024.0f); x1 = fminf(fmaxf(x1, 0.0f), 1024.0f);
            y2 = fminf(fmaxf(y2, 0.0f), 1024.0f); x2 = fminf(fmaxf(x2, 0.0f), 1024.0f);
            float hh2 = __fsub_rn(y2, y1), ww2 = __fsub_rn(x2, x1);
            float sc = (hh2 >= 16.0f && ww2 >= 16.0f) ? fg : NEGV;
            int A = abase + (gy * W + gx) * 3 + a;
            scores_all[A] = sc;
            boxes_all[A] = make_float4(y1, x1, y2, x2);
        }
    }
}

// ================= K2: score histogram (4096 buckets) =================
__global__ void hist_k(const float* __restrict__ scores, u32* __restrict__ hist) {
    __shared__ u32 h[4096];
    int tid = threadIdx.x;
    for (int i = tid; i < 4096; i += 256) h[i] = 0u;
    __syncthreads();
    int gid = blockIdx.x * 256 + tid;
    int gs = gridDim.x * 256;
    for (int i = gid; i < N_ANCH; i += gs)
        atomicAdd(&h[bucket_of(scores[i])], 1u);
    __syncthreads();
    for (int i = tid; i < 4096; i += 256) if (h[i]) atomicAdd(&hist[i], h[i]);
}

// ================= K3: find cutoff bucket (single wave) =================
__global__ void select_bucket(const u32* __restrict__ hist, u32* __restrict__ cnts) {
    int lane = threadIdx.x;
    u32 S = 0;
    for (int c = 0; c < 64; ++c) {
        int bin = 4095 - (c * 64 + lane);
        u32 cnt = hist[bin];
        u32 cum = cnt;
        for (int off = 1; off < 64; off <<= 1) {
            u32 n = __shfl_up(cum, off, 64);
            if (lane >= off) cum += n;
        }
        u64 ball = __ballot(S + cum >= (u32)PRE_NMS);
        if (ball) {
            int l = __ffsll((long long)ball) - 1;
            if (lane == 0) cnts[2] = (u32)(4095 - (c * 64 + l));
            return;
        }
        S += __shfl(cum, 63, 64);
    }
    if (lane == 0) cnts[2] = 0u;
}

// ================= K4: compact candidates (bucket >= B) =================
__global__ void compact_k(const float* __restrict__ scores, u32* __restrict__ cnts,
                          u64* __restrict__ cand) {
    int B = (int)cnts[2];
    int gid = blockIdx.x * blockDim.x + threadIdx.x;
    int gs = gridDim.x * blockDim.x;
    for (int i = gid; i < N_ANCH; i += gs) {
        float s = scores[i];
        if (bucket_of(s) >= B) {
            u32 pos = atomicAdd(&cnts[0], 1u);
            if (pos < 8192u) {
                u32 u = __float_as_uint(s);
                u32 key = (u & 0x80000000u) ? ~u : (u | 0x80000000u);
                cand[pos] = ((u64)key << 32) | (u64)((u32)(~i));
            }
        }
    }
}

// ================= K5: bitonic sort (desc) + gather top-6000 =================
__global__ __launch_bounds__(1024) void sort_gather(
    const u64* __restrict__ cand, const u32* __restrict__ cnts,
    const float* __restrict__ sall, const float4* __restrict__ ball,
    float* __restrict__ nsc, float4* __restrict__ nbx, u32* __restrict__ nvalid)
{
    __shared__ u64 srt[8192];
    int tid = threadIdx.x;
    u32 total = cnts[0]; if (total > 8192u) total = 8192u;
    for (int i = tid; i < 8192; i += 1024) srt[i] = (i < (int)total) ? cand[i] : 0ULL;
    __syncthreads();
    for (int k = 2; k <= 8192; k <<= 1) {
        for (int j = k >> 1; j > 0; j >>= 1) {
            for (int i = tid; i < 8192; i += 1024) {
                int l = i ^ j;
                if (l > i) {
                    u64 a = srt[i], b = srt[l];
                    bool descRegion = (i & k) == 0;
                    if (descRegion ? (a < b) : (a > b)) { srt[i] = b; srt[l] = a; }
                }
            }
            __syncthreads();
        }
    }
    int local = 0;
    for (int i = tid; i < PRE_NMS; i += 1024) {
        u64 comp = srt[i];
        u32 idx = ~((u32)(comp & 0xFFFFFFFFULL));
        float s; float4 bx;
        if (idx < (u32)N_ANCH) { s = sall[idx]; bx = ball[idx]; }
        else { s = NEGV; bx = make_float4(0.f, 0.f, 0.f, 0.f); }
        nsc[i] = s;
        nbx[i] = bx;
        if (s > -5.0e8f) local++;
    }
    for (int off = 32; off > 0; off >>= 1) local += __shfl_down(local, off, 64);
    if ((tid & 63) == 0) atomicAdd(nvalid, (u32)local);
}

// ================= K6: IoU suppression bitmask matrix =================
__global__ void ioumat(const float4* __restrict__ bxs, u64* __restrict__ mat) {
    int i = blockIdx.x;
    int w = threadIdx.x;
    if (w >= 94) return;
    float4 bi = bxs[i];
    float a1 = (bi.z - bi.x) * (bi.w - bi.y);
    u64 bits = 0ULL;
    int j0 = w * 64;
    for (int b = 0; b < 64; ++b) {
        int j = j0 + b;
        if (j < PRE_NMS) {
            float4 bj = bxs[j];
            float ty = fmaxf(bi.x, bj.x), tx = fmaxf(bi.y, bj.y);
            float by = fminf(bi.z, bj.z), bx = fminf(bi.w, bj.w);
            float inter = fmaxf(by - ty, 0.0f) * fmaxf(bx - tx, 0.0f);
            float a2 = (bj.z - bj.x) * (bj.w - bj.y);
            float iou = inter / fmaxf(a1 + a2 - inter, 1e-9f);
            if (iou > 0.7f) bits |= (1ULL << b);
        }
    }
    mat[(size_t)i * 94 + w] = bits;
}

// ================= K7: greedy NMS, suppression state in registers =================
__global__ void greedy(const u64* __restrict__ mat, const float* __restrict__ nbxf,
                       const u32* __restrict__ nvalid, float* __restrict__ out) {
    int lane = threadIdx.x;   // 64
    u64 rem0 = 0ULL, rem1 = 0ULL;   // lane owns words {lane, 64+lane}
    int nv = (int)*nvalid; if (nv > PRE_NMS) nv = PRE_NMS;
    int kept = 0;
    for (int widx = 0; widx * 64 < nv && kept < POST_NMS; ++widx) {
        u64 word = (widx < 64) ? __shfl(rem0, widx, 64) : __shfl(rem1, widx - 64, 64);
        int bmax = nv - widx * 64; if (bmax > 64) bmax = 64;
        for (int b = 0; b < bmax; ++b) {
            if (!((word >> b) & 1ULL)) {
                int i = widx * 64 + b;
                const u64* row = mat + (size_t)i * 94;
                rem0 |= row[lane];
                if (lane < 30) rem1 |= row[64 + lane];
                if (lane < 4) out[kept * 4 + lane] = nbxf[i * 4 + lane];
                ++kept;
                if (kept == POST_NMS) break;
                word = (widx < 64) ? __shfl(rem0, widx, 64) : __shfl(rem1, widx - 64, 64);
            }
        }
        if (kept == POST_NMS) break;
    }
    for (int idx = kept * 4 + lane; idx < POST_NMS * 4; idx += 64) out[idx] = 0.0f;
}

// ================= host =================
extern "C" void kernel_launch(void* const* d_in, const int* in_sizes, int n_in,
                              void* d_out, int out_size, void* d_ws, size_t ws_size,
                              hipStream_t stream) {
    const float* p2 = (const float*)d_in[0];
    const float* p3 = (const float*)d_in[1];
    const float* p4 = (const float*)d_in[2];
    const float* p5 = (const float*)d_in[3];
    const float* p6 = (const float*)d_in[4];
    const float* cw = (const float*)d_in[5];
    const float* cb = (const float*)d_in[6];
    const float* lw = (const float*)d_in[7];
    const float* lb = (const float*)d_in[8];
    const float* sw = (const float*)d_in[9];
    const float* sb = (const float*)d_in[10];
    float* out = (float*)d_out;
    char* ws = (char*)d_ws;

    float*  scores_all = (float*)(ws + 0);
    float4* boxes_all  = (float4*)(ws + 0x100000);
    u32*    hist       = (u32*)(ws + 0x500000);
    u32*    cnts       = (u32*)(ws + 0x504000);
    u64*    cand       = (u64*)(ws + 0x505000);
    float*  nsc        = (float*)(ws + 0x520000);
    float4* nbx        = (float4*)(ws + 0x526000);
    u64*    mat        = (u64*)(ws + 0x540000);
    float*  wtk        = (float*)(ws + 0x540000);  // aliases mat (conv-phase only)

    hipLaunchKernelGGL(wtrans, dim3(3072), dim3(256), 0, stream, cw, wtk, hist);
    hipLaunchKernelGGL(conv_head, dim3(2728), dim3(256), 0, stream,
                       p2, p3, p4, p5, p6, wtk, cb, lw, lb, sw, sb,
                       scores_all, boxes_all);
    hipLaunchKernelGGL(hist_k, dim3(64), dim3(256), 0, stream, scores_all, hist);
    hipLaunchKernelGGL(select_bucket, dim3(1), dim3(64), 0, stream, hist, cnts);
    hipLaunchKernelGGL(compact_k, dim3(512), dim3(256), 0, stream, scores_all, cnts, cand);
    hipLaunchKernelGGL(sort_gather, dim3(1), dim3(1024), 0, stream,
                       cand, cnts, scores_all, boxes_all, nsc, nbx, cnts + 1);
    hipLaunchKernelGGL(ioumat, dim3(PRE_NMS), dim3(128), 0, stream, nbx, mat);
    hipLaunchKernelGGL(greedy, dim3(1), dim3(64), 0, stream, mat, (const float*)nbx, cnts + 1, out);
}